// Round 4
// baseline (76982.812 us; speedup 1.0000x reference)
//
#include <hip/hip_runtime.h>

#define B 128
#define L 256
#define E 256
#define H 512
#define NBLK 256
#define NTHR 512

// ---- ws float offsets ----
#define WS_CTX   0u             // [B][L][H]            16777216
#define WS_GA    16777216u      // [8][2048][128]        2097152
#define WS_GD    18874368u      // [16][512][128]        1048576
#define WS_HCAR  19922944u      // [H][B]  h carry         65536
#define WS_HT    19988480u      // [H][B]  lstm h_t        65536
#define WS_CST   20054016u      // [H][B]  c state         65536
#define WS_XT    20119552u      // [E][B]  current x       32768
#define WS_INP   20152320u      // [B][H]  attn query      65536
#define WS_HID   20217856u      // [H][B]  attn context    65536
#define WS_BAR   20283392u      // flags region (uints)

// ---- d_out float offsets ----
#define OUT_ALPHA 0u
#define OUT_PTR   8388608u
#define OUT_H     8421376u
#define OUT_C     8486912u

#define L2E 1.4426950408889634f

typedef float f4v __attribute__((ext_vector_type(4)));

__device__ __forceinline__ float fast_rcp(float x) { return __builtin_amdgcn_rcpf(x); }

__device__ __forceinline__ float ftanh(float x) {
  float e = exp2f(x * (2.0f * L2E));
  return 1.0f - 2.0f * fast_rcp(e + 1.0f);
}
__device__ __forceinline__ float fsig(float x) {
  float e = exp2f(-x * L2E);
  return fast_rcp(1.0f + e);
}

// ---- coherent (LLC) scalar access, no cache maintenance ----
__device__ __forceinline__ float gload(const float* p) {
  return __hip_atomic_load((const float*)p, __ATOMIC_RELAXED, __HIP_MEMORY_SCOPE_AGENT);
}
__device__ __forceinline__ void gstore(float* p, float v) {
  __hip_atomic_store(p, v, __ATOMIC_RELAXED, __HIP_MEMORY_SCOPE_AGENT);
}
__device__ __forceinline__ unsigned uload(const unsigned* p) {
  return __hip_atomic_load((const unsigned*)p, __ATOMIC_RELAXED, __HIP_MEMORY_SCOPE_AGENT);
}
__device__ __forceinline__ void ustore(unsigned* p, unsigned v) {
  __hip_atomic_store(p, v, __ATOMIC_RELAXED, __HIP_MEMORY_SCOPE_AGENT);
}

// ---- fence-free flag barrier: no wbl2/inv, L2 stays warm ----
__device__ __forceinline__ void flag_barrier(unsigned* flags, unsigned* gen, unsigned tgt) {
  asm volatile("s_waitcnt vmcnt(0) lgkmcnt(0)" ::: "memory");  // per-wave drain
  __syncthreads();
  if (threadIdx.x == 0) ustore(&flags[blockIdx.x * 16], tgt);
  if (blockIdx.x == 0) {
    if (threadIdx.x < NBLK) {
      while (uload(&flags[threadIdx.x * 16]) < tgt) __builtin_amdgcn_s_sleep(2);
    }
    __syncthreads();
    if (threadIdx.x == 0) ustore(gen, tgt);
  } else {
    if (threadIdx.x == 0) {
      while (uload(gen) < tgt) __builtin_amdgcn_s_sleep(2);
    }
  }
  __syncthreads();
}

// ================= precompute ctx[b][l][g] (proven) =================
__global__ __launch_bounds__(256) void k_ctx(const float* __restrict__ context,
                                             const float* __restrict__ Wc,
                                             const float* __restrict__ bc,
                                             float* __restrict__ ws) {
  __shared__ float a_lds[64][33];
  __shared__ float b_lds[32][68];
  int t = threadIdx.x;
  int m0 = blockIdx.x * 64;
  int n0 = blockIdx.y * 64;
  int tx = t & 15, ty = t >> 4;
  float acc[4][4] = {};
  for (int kc = 0; kc < 16; ++kc) {
    int k0 = kc * 32;
    __syncthreads();
#pragma unroll
    for (int i = 0; i < 2; ++i) {
      int f4 = t + i * 256;
      int mm = f4 >> 3;
      int k4 = (f4 & 7) * 4;
      float4 v = *(const float4*)&context[(size_t)(m0 + mm) * H + k0 + k4];
      a_lds[mm][k4] = v.x; a_lds[mm][k4 + 1] = v.y; a_lds[mm][k4 + 2] = v.z; a_lds[mm][k4 + 3] = v.w;
    }
#pragma unroll
    for (int i = 0; i < 2; ++i) {
      int f4 = t + i * 256;
      int nn = f4 >> 3;
      int k4 = (f4 & 7) * 4;
      float4 v = *(const float4*)&Wc[(size_t)(n0 + nn) * H + k0 + k4];
      b_lds[k4][nn] = v.x; b_lds[k4 + 1][nn] = v.y; b_lds[k4 + 2][nn] = v.z; b_lds[k4 + 3][nn] = v.w;
    }
    __syncthreads();
#pragma unroll
    for (int kk = 0; kk < 32; ++kk) {
      float4 bv = *(const float4*)&b_lds[kk][tx * 4];
      float a0 = a_lds[ty * 4 + 0][kk], a1 = a_lds[ty * 4 + 1][kk];
      float a2 = a_lds[ty * 4 + 2][kk], a3 = a_lds[ty * 4 + 3][kk];
      acc[0][0] += a0 * bv.x; acc[0][1] += a0 * bv.y; acc[0][2] += a0 * bv.z; acc[0][3] += a0 * bv.w;
      acc[1][0] += a1 * bv.x; acc[1][1] += a1 * bv.y; acc[1][2] += a1 * bv.z; acc[1][3] += a1 * bv.w;
      acc[2][0] += a2 * bv.x; acc[2][1] += a2 * bv.y; acc[2][2] += a2 * bv.z; acc[2][3] += a2 * bv.w;
      acc[3][0] += a3 * bv.x; acc[3][1] += a3 * bv.y; acc[3][2] += a3 * bv.z; acc[3][3] += a3 * bv.w;
    }
  }
  float b0v = bc[n0 + tx * 4], b1v = bc[n0 + tx * 4 + 1], b2v = bc[n0 + tx * 4 + 2], b3v = bc[n0 + tx * 4 + 3];
#pragma unroll
  for (int i = 0; i < 4; ++i) {
    size_t o = WS_CTX + (size_t)(m0 + ty * 4 + i) * H + n0 + tx * 4;
    float4 v; v.x = acc[i][0] + b0v; v.y = acc[i][1] + b1v; v.z = acc[i][2] + b2v; v.w = acc[i][3] + b3v;
    *(float4*)&ws[o] = v;
  }
}

// ================= init state + flags =================
__global__ __launch_bounds__(256) void k_init(const float* __restrict__ dec_h,
                                              const float* __restrict__ dec_c,
                                              const float* __restrict__ dec_in,
                                              float* __restrict__ ws) {
  int flat = blockIdx.x * 256 + threadIdx.x;
  if (flat < 4608) ((unsigned*)(ws + WS_BAR))[flat] = 0u;
  if (flat < 65536) {
    int h = flat >> 7, b = flat & 127;
    ws[WS_HCAR + flat] = dec_h[(size_t)b * H + h];
  } else if (flat < 131072) {
    int f2 = flat - 65536;
    int h = f2 >> 7, b = f2 & 127;
    ws[WS_CST + f2] = dec_c[(size_t)b * H + h];
  } else if (flat < 163840) {
    int f2 = flat - 131072;
    int k = f2 >> 7, b = f2 & 127;
    ws[WS_XT + f2] = dec_in[(size_t)b * E + k];
  }
}

// ================= persistent fused decoder =================
__global__ __launch_bounds__(512, 1) void k_main(
    const float* __restrict__ Wi2h, const float* __restrict__ bi2h,
    const float* __restrict__ Wh2h, const float* __restrict__ bh2h,
    const float* __restrict__ Wout, const float* __restrict__ bout,
    const float* __restrict__ Winp, const float* __restrict__ binp,
    const float* __restrict__ Vv,   const float* __restrict__ emb,
    float* __restrict__ ws,         float* __restrict__ out) {
  __shared__ float smem[6656];
  __shared__ float s_maskP[256];     // persistent per-b mask (blocks 0..127)
  __shared__ float s_m, s_den;
  __shared__ int s_mi, s_cnt;
  __shared__ int s_wc[4], s_wb[4];

  unsigned* flags = (unsigned*)(ws + WS_BAR);
  unsigned* gen = &flags[4352];

  const int bid = blockIdx.x;
  const int t = threadIdx.x;
  const int wv = t >> 6;
  const int ln = t & 63;
  unsigned tgt = 0;

  if (bid < 128 && t < 256) s_maskP[t] = 1.0f;
  __syncthreads();

  for (int step = 0; step < L; ++step) {
    // ======== A1: gates partials GA[ks][j][b], K-split 8 ========
    {
      const int tile = bid & 31, ksA = bid >> 5;
      const int u0 = tile * 16;
      const int q = ln >> 5;
      const int b4 = (ln & 31) * 4;
      float4 a0 = {0,0,0,0}, a1 = a0, a2 = a0, a3 = a0;
#pragma unroll
      for (int ch = 0; ch < 3; ++ch) {
        const int kg0 = ksA * 96 + ch * 32;
        __syncthreads();
#pragma unroll
        for (int i = 0; i < 8; ++i) {              // stage acts 32x128 (coherent scalar)
          int fl = t + i * 512;
          int kk = fl >> 7, bb = fl & 127;
          int kg = kg0 + kk;
          float v = (kg < 256) ? gload(&ws[WS_XT + (size_t)kg * 128 + bb])
                               : gload(&ws[WS_HCAR + (size_t)(kg - 256) * 128 + bb]);
          smem[kk * 128 + bb] = v;
        }
#pragma unroll
        for (int i = 0; i < 4; ++i) {              // stage weights (normal, L2-resident)
          int fl = t + i * 512;
          int kk = fl & 31, rr = fl >> 5;
          int j = (rr >> 4) * 512 + u0 + (rr & 15);
          int kg = kg0 + kk;
          float wval = (kg < 256) ? Wi2h[(size_t)j * 256 + kg]
                                  : Wh2h[(size_t)j * 512 + (kg - 256)];
          smem[4096 + ((rr >> 3) * 2 + ((rr >> 2) & 1)) * 128 + kk * 4 + (rr & 3)] = wval;
        }
        __syncthreads();
        const float* sw = &smem[4096 + (wv * 2 + q) * 128];
#pragma unroll
        for (int kk = 0; kk < 32; ++kk) {
          float4 av = *(const float4*)&smem[kk * 128 + b4];
          float4 w4 = *(const float4*)&sw[kk * 4];
          a0.x += w4.x * av.x; a0.y += w4.x * av.y; a0.z += w4.x * av.z; a0.w += w4.x * av.w;
          a1.x += w4.y * av.x; a1.y += w4.y * av.y; a1.z += w4.y * av.z; a1.w += w4.y * av.w;
          a2.x += w4.z * av.x; a2.y += w4.z * av.y; a2.z += w4.z * av.z; a2.w += w4.z * av.w;
          a3.x += w4.w * av.x; a3.y += w4.w * av.y; a3.z += w4.w * av.z; a3.w += w4.w * av.w;
        }
      }
      const int rrb = wv * 8 + q * 4;
#pragma unroll
      for (int i = 0; i < 4; ++i) {
        int r = rrb + i;
        int j = (r >> 4) * 512 + u0 + (r & 15);
        float4 vv = (i == 0) ? a0 : (i == 1) ? a1 : (i == 2) ? a2 : a3;
        float* dst = &ws[WS_GA + ((size_t)ksA * 2048 + j) * 128 + b4];
        gstore(dst + 0, vv.x); gstore(dst + 1, vv.y);
        gstore(dst + 2, vv.z); gstore(dst + 3, vv.w);
      }
    }
    ++tgt; flag_barrier(flags, gen, tgt);

    // ======== A2: reduce partials + LSTM elementwise ========
    if (t < 256) {
      int fl = bid * 256 + t;
      int u = fl >> 7, b = fl & 127;
      float s4[4];
#pragma unroll
      for (int g = 0; g < 4; ++g) {
        int j = g * 512 + u;
        float a = bi2h[j] + bh2h[j];
#pragma unroll
        for (int p = 0; p < 8; ++p) a += gload(&ws[WS_GA + ((size_t)p * 2048 + j) * 128 + b]);
        s4[g] = a;
      }
      size_t cb = WS_CST + (size_t)u * 128 + b;
      float c_old = gload(&ws[cb]);
      float c_new = fsig(s4[1]) * c_old + fsig(s4[0]) * ftanh(s4[2]);
      gstore(&ws[cb], c_new);
      gstore(&ws[WS_HT + (size_t)u * 128 + b], fsig(s4[3]) * ftanh(c_new));
    }
    ++tgt; flag_barrier(flags, gen, tgt);

    // ======== B: inp[b][g] = W_inp @ h_t + b_inp  (64 blocks, 8 g each) ========
    if (bid < 64) {
      const int g0 = bid * 8;
      const float* wrow = &Winp[(size_t)(g0 + wv) * 512];
      float acc0 = 0.f, acc1 = 0.f;
      for (int ch = 0; ch < 16; ++ch) {
        const int k0 = ch * 32;
        __syncthreads();
#pragma unroll
        for (int i = 0; i < 8; ++i) {
          int fl = t + i * 512;
          int kk = fl >> 7, bb = fl & 127;
          smem[kk * 128 + bb] = gload(&ws[WS_HT + (size_t)(k0 + kk) * 128 + bb]);
        }
        __syncthreads();
#pragma unroll
        for (int kk = 0; kk < 32; ++kk) {
          float w = wrow[k0 + kk];
          acc0 += w * smem[kk * 128 + ln];
          acc1 += w * smem[kk * 128 + 64 + ln];
        }
      }
      float bv = binp[g0 + wv];
      gstore(&ws[WS_INP + (size_t)ln * 512 + g0 + wv], acc0 + bv);
      gstore(&ws[WS_INP + (size_t)(ln + 64) * 512 + g0 + wv], acc1 + bv);
    }
    ++tgt; flag_barrier(flags, gen, tgt);

    // ======== C: attention (one block per b, bid<128) ========
    if (bid < 128) {
      const int b = bid;
      float* s_inp   = smem;                 // 512
      float* s_v     = smem + 512;           // 512
      float* s_alpha = smem + 1280;          // 256
      float* s_sc    = smem + 1536;          // 512
      float* s_red   = smem + 2048;          // 4
      int*   s_redi  = (int*)(smem + 2052);  // 4
      int*   s_listI = (int*)(smem + 2056);  // 256

      s_inp[t] = gload(&ws[WS_INP + (size_t)b * 512 + t]);
      s_v[t] = Vv[t];
      __syncthreads();
      bool validl = (t < 256) && (s_maskP[t] != 0.f);
      unsigned long long bal = __ballot(validl);
      if (t < 256 && (t & 63) == 0) s_wc[t >> 6] = (int)__popcll(bal);
      __syncthreads();
      if (t == 0) {
        int base = 0;
#pragma unroll
        for (int i2 = 0; i2 < 4; ++i2) { s_wb[i2] = base; base += s_wc[i2]; }
        s_cnt = base;
      }
      __syncthreads();
      if (validl) {
        int idx = s_wb[t >> 6] + (int)__popcll(bal & ((1ull << (t & 63)) - 1ull));
        s_listI[idx] = t;
      }
      __syncthreads();
      const int cnt = s_cnt;

      // scores over packed valid slots (ctx: non-temporal, don't evict weights)
      {
        int slot = t & 255, gh = t >> 8;
        if (slot < cnt) {
          int l = s_listI[slot];
          const f4v* cb4 = (const f4v*)&ws[WS_CTX + ((size_t)b * 256 + l) * 512 + gh * 256];
          float part = 0.f;
#pragma unroll 4
          for (int i = 0; i < 64; ++i) {
            f4v c4 = __builtin_nontemporal_load(cb4 + i);
            float4 v4 = *(const float4*)&s_v[gh * 256 + i * 4];
            float4 p4 = *(const float4*)&s_inp[gh * 256 + i * 4];
            part += v4.x * ftanh(p4.x + c4[0]);
            part += v4.y * ftanh(p4.y + c4[1]);
            part += v4.z * ftanh(p4.z + c4[2]);
            part += v4.w * ftanh(p4.w + c4[3]);
          }
          s_sc[l * 2 + gh] = part;
        }
      }
      __syncthreads();
      float sc = 0.f; bool valid = false;
      if (t < 256) {
        sc = s_sc[t * 2] + s_sc[t * 2 + 1];
        valid = (s_maskP[t] != 0.f);
        float bs = valid ? sc : -INFINITY;
        int bi = t;
#pragma unroll
        for (int off = 32; off > 0; off >>= 1) {
          float os = __shfl_down(bs, off);
          int oi = __shfl_down(bi, off);
          if (os > bs || (os == bs && oi < bi)) { bs = os; bi = oi; }
        }
        if ((t & 63) == 0) { s_red[t >> 6] = bs; s_redi[t >> 6] = bi; }
      }
      __syncthreads();
      if (t == 0) {
        float m = s_red[0]; int mi = s_redi[0];
#pragma unroll
        for (int w = 1; w < 4; ++w) {
          if (s_red[w] > m || (s_red[w] == m && s_redi[w] < mi)) { m = s_red[w]; mi = s_redi[w]; }
        }
        s_m = m; s_mi = mi;
      }
      __syncthreads();
      float e = 0.f;
      if (t < 256) {
        e = valid ? exp2f((sc - s_m) * L2E) : 0.f;
        float ssum = e;
#pragma unroll
        for (int off = 32; off > 0; off >>= 1) ssum += __shfl_down(ssum, off);
        if ((t & 63) == 0) s_red[t >> 6] = ssum;
      }
      __syncthreads();
      if (t == 0) s_den = s_red[0] + s_red[1] + s_red[2] + s_red[3];
      __syncthreads();
      const int mi = s_mi;
      if (t < 256) {
        float alpha = e / s_den;
        s_alpha[t] = alpha;
        out[OUT_ALPHA + ((size_t)b * 256 + step) * 256 + t] = alpha;
        gstore(&ws[WS_XT + (size_t)t * 128 + b], emb[((size_t)b * 256 + mi) * 256 + t]);
      }
      if (t == 0) {
        out[OUT_PTR + (size_t)b * 256 + step] = (float)mi;
        s_maskP[mi] = 0.f;
      }
      __syncthreads();
      // hidden[h] = sum_l alpha_l * ctx[b][l][h]
      {
        float h0 = 0.f, h1 = 0.f, h2 = 0.f, h3 = 0.f;
        int i = 0;
        for (; i + 4 <= cnt; i += 4) {
          int l0 = s_listI[i], l1 = s_listI[i + 1], l2 = s_listI[i + 2], l3 = s_listI[i + 3];
          h0 += s_alpha[l0] * __builtin_nontemporal_load(&ws[WS_CTX + ((size_t)b * 256 + l0) * 512 + t]);
          h1 += s_alpha[l1] * __builtin_nontemporal_load(&ws[WS_CTX + ((size_t)b * 256 + l1) * 512 + t]);
          h2 += s_alpha[l2] * __builtin_nontemporal_load(&ws[WS_CTX + ((size_t)b * 256 + l2) * 512 + t]);
          h3 += s_alpha[l3] * __builtin_nontemporal_load(&ws[WS_CTX + ((size_t)b * 256 + l3) * 512 + t]);
        }
        for (; i < cnt; ++i) {
          int l0 = s_listI[i];
          h0 += s_alpha[l0] * __builtin_nontemporal_load(&ws[WS_CTX + ((size_t)b * 256 + l0) * 512 + t]);
        }
        gstore(&ws[WS_HID + (size_t)t * 128 + b], (h0 + h1) + (h2 + h3));
      }
    }
    ++tgt; flag_barrier(flags, gen, tgt);

    // ======== D1: hnew partials GD[ks][r][b], K-split 16 ========
    {
      const int rt = bid & 15, ksD = bid >> 4;
      const int r0 = rt * 32;
      const int b2 = ln * 2;
      const float* asrc = (ksD < 8) ? &ws[WS_HID + (size_t)ksD * 64 * 128]
                                    : &ws[WS_HT + (size_t)(ksD - 8) * 64 * 128];
      float2 c0 = {0,0}, c1 = {0,0}, c2 = {0,0}, c3 = {0,0};
#pragma unroll
      for (int ch = 0; ch < 2; ++ch) {
        __syncthreads();
#pragma unroll
        for (int i = 0; i < 8; ++i) {
          int fl = t + i * 512;
          int kk = fl >> 7, bb = fl & 127;
          smem[kk * 128 + bb] = gload(&asrc[(size_t)(ch * 32 + kk) * 128 + bb]);
        }
#pragma unroll
        for (int i = 0; i < 2; ++i) {
          int fl = t + i * 512;
          int kk = fl & 31, r = fl >> 5;
          smem[4096 + ((r >> 2) * 32 + kk) * 4 + (r & 3)] =
              Wout[(size_t)(r0 + r) * 1024 + ksD * 64 + ch * 32 + kk];
        }
        __syncthreads();
        const float* sw = &smem[4096 + wv * 128];
#pragma unroll
        for (int kk = 0; kk < 32; ++kk) {
          float2 a2v = *(const float2*)&smem[kk * 128 + b2];
          float4 w4 = *(const float4*)&sw[kk * 4];
          c0.x += w4.x * a2v.x; c0.y += w4.x * a2v.y;
          c1.x += w4.y * a2v.x; c1.y += w4.y * a2v.y;
          c2.x += w4.z * a2v.x; c2.y += w4.z * a2v.y;
          c3.x += w4.w * a2v.x; c3.y += w4.w * a2v.y;
        }
      }
#pragma unroll
      for (int i = 0; i < 4; ++i) {
        float2 cv = (i == 0) ? c0 : (i == 1) ? c1 : (i == 2) ? c2 : c3;
        float* dst = &ws[WS_GD + ((size_t)ksD * 512 + r0 + wv * 4 + i) * 128 + b2];
        gstore(dst + 0, cv.x); gstore(dst + 1, cv.y);
      }
    }
    ++tgt; flag_barrier(flags, gen, tgt);

    // ======== D2: reduce + tanh -> HCAR ========
    if (t < 256) {
      int fl = bid * 256 + t;
      int r = fl >> 7, b = fl & 127;
      float s = bout[r];
#pragma unroll
      for (int p = 0; p < 16; ++p) s += gload(&ws[WS_GD + ((size_t)p * 512 + r) * 128 + b]);
      gstore(&ws[WS_HCAR + (size_t)r * 128 + b], ftanh(s));
    }
    ++tgt; flag_barrier(flags, gen, tgt);
  }

  // ======== final h/c outputs ========
  if (t < 256) {
    int fl = bid * 256 + t;
    int r = fl >> 7, b = fl & 127;
    out[OUT_H + (size_t)b * 512 + r] = gload(&ws[WS_HCAR + (size_t)r * 128 + b]);
    out[OUT_C + (size_t)b * 512 + r] = gload(&ws[WS_CST + (size_t)r * 128 + b]);
  }
}

extern "C" void kernel_launch(void* const* d_in, const int* in_sizes, int n_in,
                              void* d_out, int out_size, void* d_ws, size_t ws_size,
                              hipStream_t stream) {
  (void)in_sizes; (void)n_in; (void)out_size; (void)ws_size;
  const float* emb    = (const float*)d_in[0];
  const float* dec_in = (const float*)d_in[1];
  const float* dec_h  = (const float*)d_in[2];
  const float* dec_c  = (const float*)d_in[3];
  const float* ctx_in = (const float*)d_in[4];
  const float* W_i2h  = (const float*)d_in[5];
  const float* b_i2h  = (const float*)d_in[6];
  const float* W_h2h  = (const float*)d_in[7];
  const float* b_h2h  = (const float*)d_in[8];
  const float* W_out  = (const float*)d_in[9];
  const float* b_out  = (const float*)d_in[10];
  const float* W_inp  = (const float*)d_in[11];
  const float* b_inp  = (const float*)d_in[12];
  const float* W_ctx  = (const float*)d_in[13];
  const float* b_ctx  = (const float*)d_in[14];
  const float* Vv     = (const float*)d_in[15];
  float* out = (float*)d_out;
  float* ws  = (float*)d_ws;

  k_ctx<<<dim3(512, 8), 256, 0, stream>>>(ctx_in, W_ctx, b_ctx, ws);
  k_init<<<768, 256, 0, stream>>>(dec_h, dec_c, dec_in, ws);
  k_main<<<NBLK, NTHR, 0, stream>>>(W_i2h, b_i2h, W_h2h, b_h2h, W_out, b_out,
                                    W_inp, b_inp, Vv, emb, ws, out);
}

// Round 6
// 22918.877 us; speedup vs baseline: 3.3589x; 3.3589x over previous
//
#include <hip/hip_runtime.h>

#define B 128
#define L 256
#define E 256
#define H 512
#define NBLK 256
#define NTHR 512

typedef float f4 __attribute__((ext_vector_type(4)));
typedef unsigned u4 __attribute__((ext_vector_type(4)));

// ---- ws float offsets ----
#define WS_CTX 0u          // [B][L][H] = 16777216
#define WS_GA  16777216u   // [8][128][2048] = 2097152 (gates partials)
#define WS_IP  16777216u   // [16][128][512] = 1048576 (overlays GA lower half)
#define WS_GD  17825792u   // [16][128][512] = 1048576 (overlays GA upper half)
#define WS_HT  18874368u   // [B][512] lstm h_t
#define WS_HH  18939904u   // [B][512] h carry
#define WS_HID 19005440u   // [B][512] attn context
#define WS_XT  19070976u   // [B][256] current x
#define WS_FLG 19103744u   // 512 uints (barrier flags)

// ---- d_out float offsets ----
#define OUT_ALPHA 0u
#define OUT_PTR   8388608u
#define OUT_H     8421376u
#define OUT_C     8486912u

#define L2E 1.4426950408889634f

__device__ __forceinline__ float fast_rcp(float x) { return __builtin_amdgcn_rcpf(x); }

__device__ __forceinline__ float ftanh(float x) {
  float e = exp2f(x * (2.0f * L2E));
  return 1.0f - 2.0f * fast_rcp(e + 1.0f);
}
__device__ __forceinline__ float fsig(float x) {
  float e = exp2f(-x * L2E);
  return fast_rcp(1.0f + e);
}

// ==== batched coherent loads: N x dwordx4 + vmcnt(0) inside ONE asm block ====
// Outputs are early-clobber so no output register aliases a pending address.
#define CLD2(va, pa)                                                          \
  asm volatile("global_load_dwordx4 %0, %2, off sc0 sc1\n\t"                  \
               "global_load_dwordx4 %1, %3, off sc0 sc1\n\t"                  \
               "s_waitcnt vmcnt(0)"                                           \
               : "=&v"(va[0]), "=&v"(va[1])                                   \
               : "v"(pa[0]), "v"(pa[1]) : "memory")

#define CLD4(va, pa)                                                          \
  asm volatile("global_load_dwordx4 %0, %4, off sc0 sc1\n\t"                  \
               "global_load_dwordx4 %1, %5, off sc0 sc1\n\t"                  \
               "global_load_dwordx4 %2, %6, off sc0 sc1\n\t"                  \
               "global_load_dwordx4 %3, %7, off sc0 sc1\n\t"                  \
               "s_waitcnt vmcnt(0)"                                           \
               : "=&v"(va[0]), "=&v"(va[1]), "=&v"(va[2]), "=&v"(va[3])       \
               : "v"(pa[0]), "v"(pa[1]), "v"(pa[2]), "v"(pa[3]) : "memory")

#define CLD6(va, pa)                                                          \
  asm volatile("global_load_dwordx4 %0, %6, off sc0 sc1\n\t"                  \
               "global_load_dwordx4 %1, %7, off sc0 sc1\n\t"                  \
               "global_load_dwordx4 %2, %8, off sc0 sc1\n\t"                  \
               "global_load_dwordx4 %3, %9, off sc0 sc1\n\t"                  \
               "global_load_dwordx4 %4, %10, off sc0 sc1\n\t"                 \
               "global_load_dwordx4 %5, %11, off sc0 sc1\n\t"                 \
               "s_waitcnt vmcnt(0)"                                           \
               : "=&v"(va[0]), "=&v"(va[1]), "=&v"(va[2]), "=&v"(va[3]),      \
                 "=&v"(va[4]), "=&v"(va[5])                                   \
               : "v"(pa[0]), "v"(pa[1]), "v"(pa[2]), "v"(pa[3]),              \
                 "v"(pa[4]), "v"(pa[5]) : "memory")

#define CLD16(va, pa)                                                         \
  asm volatile("global_load_dwordx4 %0, %16, off sc0 sc1\n\t"                 \
               "global_load_dwordx4 %1, %17, off sc0 sc1\n\t"                 \
               "global_load_dwordx4 %2, %18, off sc0 sc1\n\t"                 \
               "global_load_dwordx4 %3, %19, off sc0 sc1\n\t"                 \
               "global_load_dwordx4 %4, %20, off sc0 sc1\n\t"                 \
               "global_load_dwordx4 %5, %21, off sc0 sc1\n\t"                 \
               "global_load_dwordx4 %6, %22, off sc0 sc1\n\t"                 \
               "global_load_dwordx4 %7, %23, off sc0 sc1\n\t"                 \
               "global_load_dwordx4 %8, %24, off sc0 sc1\n\t"                 \
               "global_load_dwordx4 %9, %25, off sc0 sc1\n\t"                 \
               "global_load_dwordx4 %10, %26, off sc0 sc1\n\t"                \
               "global_load_dwordx4 %11, %27, off sc0 sc1\n\t"                \
               "global_load_dwordx4 %12, %28, off sc0 sc1\n\t"                \
               "global_load_dwordx4 %13, %29, off sc0 sc1\n\t"                \
               "global_load_dwordx4 %14, %30, off sc0 sc1\n\t"                \
               "global_load_dwordx4 %15, %31, off sc0 sc1\n\t"                \
               "s_waitcnt vmcnt(0)"                                           \
               : "=&v"(va[0]), "=&v"(va[1]), "=&v"(va[2]), "=&v"(va[3]),      \
                 "=&v"(va[4]), "=&v"(va[5]), "=&v"(va[6]), "=&v"(va[7]),      \
                 "=&v"(va[8]), "=&v"(va[9]), "=&v"(va[10]), "=&v"(va[11]),    \
                 "=&v"(va[12]), "=&v"(va[13]), "=&v"(va[14]), "=&v"(va[15])   \
               : "v"(pa[0]), "v"(pa[1]), "v"(pa[2]), "v"(pa[3]),              \
                 "v"(pa[4]), "v"(pa[5]), "v"(pa[6]), "v"(pa[7]),              \
                 "v"(pa[8]), "v"(pa[9]), "v"(pa[10]), "v"(pa[11]),            \
                 "v"(pa[12]), "v"(pa[13]), "v"(pa[14]), "v"(pa[15]) : "memory")

// ==== batched coherent stores: N x dwordx4 + expcnt(0) inside (data-reg reuse fence) ====
#define CST4_1(p0, v0)                                                        \
  asm volatile("global_store_dwordx4 %0, %1, off sc0 sc1\n\t"                 \
               "s_waitcnt expcnt(0)"                                          \
               :: "v"(p0), "v"(v0) : "memory")

#define CST4_2(p0, v0, p1, v1)                                                \
  asm volatile("global_store_dwordx4 %0, %1, off sc0 sc1\n\t"                 \
               "global_store_dwordx4 %2, %3, off sc0 sc1\n\t"                 \
               "s_waitcnt expcnt(0)"                                          \
               :: "v"(p0), "v"(v0), "v"(p1), "v"(v1) : "memory")

#define CST4_4(p0, v0, p1, v1, p2, v2, p3, v3)                                \
  asm volatile("global_store_dwordx4 %0, %1, off sc0 sc1\n\t"                 \
               "global_store_dwordx4 %2, %3, off sc0 sc1\n\t"                 \
               "global_store_dwordx4 %4, %5, off sc0 sc1\n\t"                 \
               "global_store_dwordx4 %6, %7, off sc0 sc1\n\t"                 \
               "s_waitcnt expcnt(0)"                                          \
               :: "v"(p0), "v"(v0), "v"(p1), "v"(v1),                         \
                  "v"(p2), "v"(v2), "v"(p3), "v"(v3) : "memory")

#define CST1_1(p0, v0)                                                        \
  asm volatile("global_store_dword %0, %1, off sc0 sc1\n\t"                   \
               "s_waitcnt expcnt(0)"                                          \
               :: "v"(p0), "v"(v0) : "memory")

// ---- all-to-all flag barrier (proven pattern: waitcnt inside the poll asm) ----
__device__ __forceinline__ void gbar(unsigned* flags, unsigned tgt) {
  asm volatile("s_waitcnt vmcnt(0) lgkmcnt(0) expcnt(0)" ::: "memory");
  __syncthreads();
  if (threadIdx.x == 0) {
    unsigned* p = flags + blockIdx.x;
    asm volatile("global_store_dword %0, %1, off sc0 sc1" :: "v"(p), "v"(tgt) : "memory");
  }
  if (threadIdx.x < 64) {
    const unsigned* fp = flags + threadIdx.x * 4;
    for (;;) {
      u4 f;
      asm volatile("global_load_dwordx4 %0, %1, off sc0 sc1\n\ts_waitcnt vmcnt(0)"
                   : "=&v"(f) : "v"(fp) : "memory");
      bool ok = (f[0] >= tgt) && (f[1] >= tgt) && (f[2] >= tgt) && (f[3] >= tgt);
      if (__all(ok)) break;
      __builtin_amdgcn_s_sleep(2);
    }
  }
  __syncthreads();
}

// ================= precompute ctx[b][l][g] (proven) =================
__global__ __launch_bounds__(256) void k_ctx(const float* __restrict__ context,
                                             const float* __restrict__ Wc,
                                             const float* __restrict__ bc,
                                             float* __restrict__ ws) {
  __shared__ float a_lds[64][33];
  __shared__ float b_lds[32][68];
  int t = threadIdx.x;
  int m0 = blockIdx.x * 64;
  int n0 = blockIdx.y * 64;
  int tx = t & 15, ty = t >> 4;
  float acc[4][4] = {};
  for (int kc = 0; kc < 16; ++kc) {
    int k0 = kc * 32;
    __syncthreads();
#pragma unroll
    for (int i = 0; i < 2; ++i) {
      int f40 = t + i * 256;
      int mm = f40 >> 3;
      int k4 = (f40 & 7) * 4;
      float4 v = *(const float4*)&context[(size_t)(m0 + mm) * H + k0 + k4];
      a_lds[mm][k4] = v.x; a_lds[mm][k4 + 1] = v.y; a_lds[mm][k4 + 2] = v.z; a_lds[mm][k4 + 3] = v.w;
    }
#pragma unroll
    for (int i = 0; i < 2; ++i) {
      int f40 = t + i * 256;
      int nn = f40 >> 3;
      int k4 = (f40 & 7) * 4;
      float4 v = *(const float4*)&Wc[(size_t)(n0 + nn) * H + k0 + k4];
      b_lds[k4][nn] = v.x; b_lds[k4 + 1][nn] = v.y; b_lds[k4 + 2][nn] = v.z; b_lds[k4 + 3][nn] = v.w;
    }
    __syncthreads();
#pragma unroll
    for (int kk = 0; kk < 32; ++kk) {
      float4 bv = *(const float4*)&b_lds[kk][tx * 4];
      float a0 = a_lds[ty * 4 + 0][kk], a1 = a_lds[ty * 4 + 1][kk];
      float a2 = a_lds[ty * 4 + 2][kk], a3 = a_lds[ty * 4 + 3][kk];
      acc[0][0] += a0 * bv.x; acc[0][1] += a0 * bv.y; acc[0][2] += a0 * bv.z; acc[0][3] += a0 * bv.w;
      acc[1][0] += a1 * bv.x; acc[1][1] += a1 * bv.y; acc[1][2] += a1 * bv.z; acc[1][3] += a1 * bv.w;
      acc[2][0] += a2 * bv.x; acc[2][1] += a2 * bv.y; acc[2][2] += a2 * bv.z; acc[2][3] += a2 * bv.w;
      acc[3][0] += a3 * bv.x; acc[3][1] += a3 * bv.y; acc[3][2] += a3 * bv.z; acc[3][3] += a3 * bv.w;
    }
  }
  float b0v = bc[n0 + tx * 4], b1v = bc[n0 + tx * 4 + 1], b2v = bc[n0 + tx * 4 + 2], b3v = bc[n0 + tx * 4 + 3];
#pragma unroll
  for (int i = 0; i < 4; ++i) {
    size_t o = WS_CTX + (size_t)(m0 + ty * 4 + i) * H + n0 + tx * 4;
    float4 v; v.x = acc[i][0] + b0v; v.y = acc[i][1] + b1v; v.z = acc[i][2] + b2v; v.w = acc[i][3] + b3v;
    *(float4*)&ws[o] = v;
  }
}

// ================= init: HH=dec_h, XT=dec_in, flags=0 =================
__global__ __launch_bounds__(256) void k_init(const float* __restrict__ dec_h,
                                              const float* __restrict__ dec_in,
                                              float* __restrict__ ws) {
  int flat = blockIdx.x * 256 + threadIdx.x;
  if (flat < 65536) {
    ws[WS_HH + flat] = dec_h[flat];
  } else if (flat < 98304) {
    ws[WS_XT + (flat - 65536)] = dec_in[flat - 65536];
  } else if (flat < 98816) {
    ((unsigned*)(ws + WS_FLG))[flat - 98304] = 0u;
  }
}

// ================= persistent fused decoder =================
__global__ __launch_bounds__(512, 1) void k_main(
    const float* __restrict__ Wi2h, const float* __restrict__ bi2h,
    const float* __restrict__ Wh2h, const float* __restrict__ bh2h,
    const float* __restrict__ Wout, const float* __restrict__ bout,
    const float* __restrict__ Winp, const float* __restrict__ binp,
    const float* __restrict__ Vv,   const float* __restrict__ emb,
    const float* __restrict__ dec_c,
    float* __restrict__ ws,         float* __restrict__ out) {
  __shared__ float s_act[12416];
  __shared__ float s_maskP[256];
  __shared__ float s_mw[8], s_dw[8];
  __shared__ float s_red[4];
  __shared__ int   s_redi[4];
  __shared__ int   s_wc[4], s_wb[4];
  __shared__ int   s_mi, s_cnt;

  unsigned* flags = (unsigned*)(ws + WS_FLG);
  const int bid = blockIdx.x;
  const int t = threadIdx.x;
  const int wv = t >> 6, ln = t & 63;
  unsigned tgt = 0;

  float creg[4];

  if (bid < 128 && t < 256) s_maskP[t] = 1.0f;
  __syncthreads();

  for (int step = 0; step < L; ++step) {
    // ======== P1: gates partials GA[kt][b][j]; 32 u-tiles x 8 k-slices ========
    {
      const int u0 = (bid & 31) * 16;
      const int kt = bid >> 5;
      const int k0 = kt * 96;
      f4 va[6]; const float* pa[6]; int sb[6], sq[6];
#pragma unroll
      for (int it = 0; it < 6; ++it) {
        unsigned slot = (unsigned)(t + it * 512);
        int b = (int)(slot / 24u);
        int kq = (int)(slot - (unsigned)b * 24u);
        int kg = k0 + kq * 4;
        sb[it] = b; sq[it] = kq;
        pa[it] = (kg < 256) ? ws + WS_XT + (size_t)b * 256 + kg
                            : ws + WS_HH + (size_t)b * 512 + (kg - 256);
      }
      CLD6(va, pa);
      __builtin_amdgcn_sched_barrier(0);
#pragma unroll
      for (int it = 0; it < 6; ++it) {
        int o = sb[it] * 97 + sq[it] * 4;
        s_act[o] = va[it][0]; s_act[o + 1] = va[it][1];
        s_act[o + 2] = va[it][2]; s_act[o + 3] = va[it][3];
      }
      __syncthreads();
      const int g = wv >> 1;
      const int ub = u0 + (wv & 1) * 8;
      float a0[8] = {0,0,0,0,0,0,0,0}, a1[8] = {0,0,0,0,0,0,0,0};
      const float* sa0 = s_act + ln * 97;
      const float* sa1 = s_act + (ln + 64) * 97;
      int kx = 256 - k0; kx = kx < 0 ? 0 : (kx > 96 ? 96 : kx);
      if (kx > 0) {
        const float* wr[8];
#pragma unroll
        for (int jj = 0; jj < 8; ++jj) wr[jj] = Wi2h + (size_t)(g * 512 + ub + jj) * 256 + k0;
        for (int kk = 0; kk < kx; ++kk) {
          float x0 = sa0[kk], x1 = sa1[kk];
#pragma unroll
          for (int jj = 0; jj < 8; ++jj) { float w = wr[jj][kk]; a0[jj] += w * x0; a1[jj] += w * x1; }
        }
      }
      if (kx < 96) {
        const float* wr[8];
#pragma unroll
        for (int jj = 0; jj < 8; ++jj) wr[jj] = Wh2h + (size_t)(g * 512 + ub + jj) * 512 + (k0 + kx - 256);
        const float* sb0 = sa0 + kx; const float* sb1 = sa1 + kx;
        const int kn = 96 - kx;
        for (int kk = 0; kk < kn; ++kk) {
          float x0 = sb0[kk], x1 = sb1[kk];
#pragma unroll
          for (int jj = 0; jj < 8; ++jj) { float w = wr[jj][kk]; a0[jj] += w * x0; a1[jj] += w * x1; }
        }
      }
      f4 q0, q1, q2, q3;
      q0[0]=a0[0]; q0[1]=a0[1]; q0[2]=a0[2]; q0[3]=a0[3];
      q1[0]=a0[4]; q1[1]=a0[5]; q1[2]=a0[6]; q1[3]=a0[7];
      q2[0]=a1[0]; q2[1]=a1[1]; q2[2]=a1[2]; q2[3]=a1[3];
      q3[0]=a1[4]; q3[1]=a1[5]; q3[2]=a1[6]; q3[3]=a1[7];
      float* p0 = ws + WS_GA + ((size_t)(kt * 128 + ln) * 2048) + g * 512 + ub;
      float* p1 = p0 + 4;
      float* p2 = ws + WS_GA + ((size_t)(kt * 128 + ln + 64) * 2048) + g * 512 + ub;
      float* p3 = p2 + 4;
      CST4_4(p0, q0, p1, q1, p2, q2, p3, q3);
    }
    ++tgt; gbar(flags, tgt);

    // ======== P2: reduce 8 partials + LSTM; c in VGPRs ========
    if (t < 64) {
      const int b = bid >> 1, uh = bid & 1;
      const int u4 = uh * 256 + t * 4;
      f4 s0 = {0,0,0,0}, s1 = s0, s2 = s0, s3 = s0;
#pragma unroll
      for (int half = 0; half < 2; ++half) {
        f4 va[16]; const float* pa[16];
#pragma unroll
        for (int q = 0; q < 16; ++q) {
          int kt = half * 4 + (q >> 2), g = q & 3;
          pa[q] = ws + WS_GA + ((size_t)(kt * 128 + b) * 2048) + g * 512 + u4;
        }
        CLD16(va, pa);
        __builtin_amdgcn_sched_barrier(0);
#pragma unroll
        for (int q = 0; q < 16; ++q) {
          int g = q & 3;
          if (g == 0) s0 += va[q]; else if (g == 1) s1 += va[q];
          else if (g == 2) s2 += va[q]; else s3 += va[q];
        }
      }
#pragma unroll
      for (int i = 0; i < 4; ++i) {
        s0[i] += bi2h[0 * 512 + u4 + i] + bh2h[0 * 512 + u4 + i];
        s1[i] += bi2h[1 * 512 + u4 + i] + bh2h[1 * 512 + u4 + i];
        s2[i] += bi2h[2 * 512 + u4 + i] + bh2h[2 * 512 + u4 + i];
        s3[i] += bi2h[3 * 512 + u4 + i] + bh2h[3 * 512 + u4 + i];
      }
      if (step == 0) {
#pragma unroll
        for (int i = 0; i < 4; ++i) creg[i] = dec_c[(size_t)b * 512 + u4 + i];
      }
      f4 ht;
#pragma unroll
      for (int i = 0; i < 4; ++i) {
        float cn = fsig(s1[i]) * creg[i] + fsig(s0[i]) * ftanh(s2[i]);
        creg[i] = cn;
        ht[i] = fsig(s3[i]) * ftanh(cn);
      }
      float* hp = ws + WS_HT + (size_t)b * 512 + u4;
      CST4_1(hp, ht);
      if (step == L - 1) {
        float4 cv; cv.x = creg[0]; cv.y = creg[1]; cv.z = creg[2]; cv.w = creg[3];
        *(float4*)&out[OUT_C + (size_t)b * 512 + u4] = cv;
      }
    }
    ++tgt; gbar(flags, tgt);

    // ======== P3: inp partials IP[kt][b][g]; 16 g-tiles x 16 k-slices ========
    {
      const int g0 = (bid & 15) * 32;
      const int kt = bid >> 4;
      const int k3 = kt * 32;
      f4 va[2]; const float* pa[2];
#pragma unroll
      for (int it = 0; it < 2; ++it) {
        int flat = t + it * 512;
        int b = flat >> 3, kq = flat & 7;
        pa[it] = ws + WS_HT + (size_t)b * 512 + k3 + kq * 4;
      }
      CLD2(va, pa);
      __builtin_amdgcn_sched_barrier(0);
#pragma unroll
      for (int it = 0; it < 2; ++it) {
        int flat = t + it * 512;
        int b = flat >> 3, kq = flat & 7;
        int o = b * 33 + kq * 4;
        s_act[o] = va[it][0]; s_act[o + 1] = va[it][1];
        s_act[o + 2] = va[it][2]; s_act[o + 3] = va[it][3];
      }
      __syncthreads();
      const int gb = g0 + wv * 4;
      float a0[4] = {0,0,0,0}, a1[4] = {0,0,0,0};
      const float* wr[4];
#pragma unroll
      for (int rr = 0; rr < 4; ++rr) wr[rr] = Winp + (size_t)(gb + rr) * 512 + k3;
      const float* sa0 = s_act + ln * 33;
      const float* sa1 = s_act + (ln + 64) * 33;
      for (int kk = 0; kk < 32; ++kk) {
        float x0 = sa0[kk], x1 = sa1[kk];
#pragma unroll
        for (int rr = 0; rr < 4; ++rr) { float w = wr[rr][kk]; a0[rr] += w * x0; a1[rr] += w * x1; }
      }
      f4 q0, q1;
      q0[0]=a0[0]; q0[1]=a0[1]; q0[2]=a0[2]; q0[3]=a0[3];
      q1[0]=a1[0]; q1[1]=a1[1]; q1[2]=a1[2]; q1[3]=a1[3];
      float* p0 = ws + WS_IP + ((size_t)(kt * 128 + ln) * 512) + gb;
      float* p1 = ws + WS_IP + ((size_t)(kt * 128 + ln + 64) * 512) + gb;
      CST4_2(p0, q0, p1, q1);
    }
    ++tgt; gbar(flags, tgt);

    // ======== P4: attention (blocks 0..127), fused single ctx pass ========
    if (bid < 128) {
      const int b = bid;
      float* s_inp  = s_act;
      float* s_sc   = s_act + 512;
      int*   s_li   = (int*)(s_act + 768);
      float* s_hidp = s_act + 1024;
      if (t < 128) {
        f4 acc = {0,0,0,0};
        f4 va[16]; const float* pa[16];
#pragma unroll
        for (int q = 0; q < 16; ++q)
          pa[q] = ws + WS_IP + ((size_t)(q * 128 + b) * 512) + t * 4;
        CLD16(va, pa);
        __builtin_amdgcn_sched_barrier(0);
#pragma unroll
        for (int q = 0; q < 16; ++q) acc += va[q];
        const float4 bv = *(const float4*)&binp[t * 4];
        s_inp[t * 4 + 0] = acc[0] + bv.x; s_inp[t * 4 + 1] = acc[1] + bv.y;
        s_inp[t * 4 + 2] = acc[2] + bv.z; s_inp[t * 4 + 3] = acc[3] + bv.w;
      }
      __syncthreads();
      const int d0 = ln * 8;
      float inp8[8], v8[8];
#pragma unroll
      for (int i = 0; i < 8; ++i) { inp8[i] = s_inp[d0 + i]; v8[i] = Vv[d0 + i]; }
      bool validl = (t < 256) && (s_maskP[t] != 0.f);
      unsigned long long bal = __ballot(validl);
      if (t < 256 && (t & 63) == 0) s_wc[t >> 6] = (int)__popcll(bal);
      __syncthreads();
      if (t == 0) {
        int base = 0;
#pragma unroll
        for (int i = 0; i < 4; ++i) { s_wb[i] = base; base += s_wc[i]; }
        s_cnt = base;
      }
      __syncthreads();
      if (validl) {
        int idx = s_wb[t >> 6] + (int)__popcll(bal & ((1ull << (t & 63)) - 1ull));
        s_li[idx] = t;
      }
      __syncthreads();
      const int cnt = s_cnt;
      float m = -INFINITY, den = 0.f;
      float hid[8] = {0,0,0,0,0,0,0,0};
      for (int slot = wv; slot < cnt; slot += 8) {
        int l = s_li[slot];
        const float* cp = ws + WS_CTX + ((size_t)(b * 256 + l) * 512) + d0;
        f4 c0 = *(const f4*)cp;
        f4 c1 = *(const f4*)(cp + 4);
        float part = v8[0] * ftanh(inp8[0] + c0[0]) + v8[1] * ftanh(inp8[1] + c0[1])
                   + v8[2] * ftanh(inp8[2] + c0[2]) + v8[3] * ftanh(inp8[3] + c0[3])
                   + v8[4] * ftanh(inp8[4] + c1[0]) + v8[5] * ftanh(inp8[5] + c1[1])
                   + v8[6] * ftanh(inp8[6] + c1[2]) + v8[7] * ftanh(inp8[7] + c1[3]);
#pragma unroll
        for (int off = 32; off > 0; off >>= 1) part += __shfl_xor(part, off);
        if (ln == 0) s_sc[l] = part;
        float mn = fmaxf(m, part);
        float scale = exp2f((m - mn) * L2E);
        float e = exp2f((part - mn) * L2E);
        den = den * scale + e;
        hid[0] = hid[0] * scale + e * c0[0]; hid[1] = hid[1] * scale + e * c0[1];
        hid[2] = hid[2] * scale + e * c0[2]; hid[3] = hid[3] * scale + e * c0[3];
        hid[4] = hid[4] * scale + e * c1[0]; hid[5] = hid[5] * scale + e * c1[1];
        hid[6] = hid[6] * scale + e * c1[2]; hid[7] = hid[7] * scale + e * c1[3];
        m = mn;
      }
      if (ln == 0) { s_mw[wv] = m; s_dw[wv] = den; }
      __syncthreads();
      float M = s_mw[0];
#pragma unroll
      for (int w = 1; w < 8; ++w) M = fmaxf(M, s_mw[w]);
      float D = 0.f;
#pragma unroll
      for (int w = 0; w < 8; ++w) D += s_dw[w] * exp2f((s_mw[w] - M) * L2E);
      float fac = exp2f((m - M) * L2E);
#pragma unroll
      for (int i = 0; i < 8; ++i) s_hidp[wv * 512 + d0 + i] = hid[i] * fac;
      __syncthreads();
      float rD = 1.0f / D;
      {
        float hs = 0.f;
#pragma unroll
        for (int w = 0; w < 8; ++w) hs += s_hidp[w * 512 + t];
        float* hp = ws + WS_HID + (size_t)b * 512 + t;
        float hv = hs * rD;
        CST1_1(hp, hv);
      }
      float sc = 0.f; bool valid = false;
      if (t < 256) {
        valid = (s_maskP[t] != 0.f);
        sc = s_sc[t];
        float alpha = valid ? exp2f((sc - M) * L2E) * rD : 0.f;
        out[OUT_ALPHA + ((size_t)b * 256 + step) * 256 + t] = alpha;
        float bs = valid ? sc : -INFINITY;
        int bi = t;
#pragma unroll
        for (int off = 32; off > 0; off >>= 1) {
          float os = __shfl_down(bs, off);
          int oi = __shfl_down(bi, off);
          if (os > bs || (os == bs && oi < bi)) { bs = os; bi = oi; }
        }
        if ((t & 63) == 0) { s_red[t >> 6] = bs; s_redi[t >> 6] = bi; }
      }
      __syncthreads();
      if (t == 0) {
        float mm = s_red[0]; int mi = s_redi[0];
#pragma unroll
        for (int w = 1; w < 4; ++w) {
          if (s_red[w] > mm || (s_red[w] == mm && s_redi[w] < mi)) { mm = s_red[w]; mi = s_redi[w]; }
        }
        s_mi = mi;
      }
      __syncthreads();
      const int mi = s_mi;
      if (t < 256) {
        float* xp = ws + WS_XT + (size_t)b * 256 + t;
        float xv = emb[((size_t)b * 256 + mi) * 256 + t];
        CST1_1(xp, xv);
      }
      if (t == 0) {
        out[OUT_PTR + (size_t)b * 256 + step] = (float)mi;
        s_maskP[mi] = 0.f;
      }
    }
    ++tgt; gbar(flags, tgt);

    // ======== P5: hnew partials GD[kt][b][r]; 16 r-tiles x 16 k-slices ========
    {
      const int r0 = (bid & 15) * 32;
      const int kt = bid >> 4;
      const int k5 = kt * 64;
      f4 va[4]; const float* pa[4];
#pragma unroll
      for (int it = 0; it < 4; ++it) {
        int flat = t + it * 512;
        int b = flat >> 4, kq = flat & 15;
        int kg = k5 + kq * 4;
        pa[it] = (kg < 512) ? ws + WS_HID + (size_t)b * 512 + kg
                            : ws + WS_HT + (size_t)b * 512 + (kg - 512);
      }
      CLD4(va, pa);
      __builtin_amdgcn_sched_barrier(0);
#pragma unroll
      for (int it = 0; it < 4; ++it) {
        int flat = t + it * 512;
        int b = flat >> 4, kq = flat & 15;
        int o = b * 65 + kq * 4;
        s_act[o] = va[it][0]; s_act[o + 1] = va[it][1];
        s_act[o + 2] = va[it][2]; s_act[o + 3] = va[it][3];
      }
      __syncthreads();
      const int rb = r0 + wv * 4;
      float a0[4] = {0,0,0,0}, a1[4] = {0,0,0,0};
      const float* wr[4];
#pragma unroll
      for (int rr = 0; rr < 4; ++rr) wr[rr] = Wout + (size_t)(rb + rr) * 1024 + k5;
      const float* sa0 = s_act + ln * 65;
      const float* sa1 = s_act + (ln + 64) * 65;
      for (int kk = 0; kk < 64; ++kk) {
        float x0 = sa0[kk], x1 = sa1[kk];
#pragma unroll
        for (int rr = 0; rr < 4; ++rr) { float w = wr[rr][kk]; a0[rr] += w * x0; a1[rr] += w * x1; }
      }
      f4 q0, q1;
      q0[0]=a0[0]; q0[1]=a0[1]; q0[2]=a0[2]; q0[3]=a0[3];
      q1[0]=a1[0]; q1[1]=a1[1]; q1[2]=a1[2]; q1[3]=a1[3];
      float* p0 = ws + WS_GD + ((size_t)(kt * 128 + ln) * 512) + rb;
      float* p1 = ws + WS_GD + ((size_t)(kt * 128 + ln + 64) * 512) + rb;
      CST4_2(p0, q0, p1, q1);
    }
    ++tgt; gbar(flags, tgt);

    // ======== P6: reduce 16 partials + tanh -> h carry ========
    if (t < 64) {
      const int b = bid >> 1, rh = bid & 1;
      const int r4 = rh * 256 + t * 4;
      f4 s = {0,0,0,0};
      f4 va[16]; const float* pa[16];
#pragma unroll
      for (int q = 0; q < 16; ++q)
        pa[q] = ws + WS_GD + ((size_t)(q * 128 + b) * 512) + r4;
      CLD16(va, pa);
      __builtin_amdgcn_sched_barrier(0);
#pragma unroll
      for (int q = 0; q < 16; ++q) s += va[q];
      const float4 bo = *(const float4*)&bout[r4];
      f4 h;
      h[0] = ftanh(s[0] + bo.x); h[1] = ftanh(s[1] + bo.y);
      h[2] = ftanh(s[2] + bo.z); h[3] = ftanh(s[3] + bo.w);
      float* hp = ws + WS_HH + (size_t)b * 512 + r4;
      CST4_1(hp, h);
      if (step == L - 1) {
        float4 hv; hv.x = h[0]; hv.y = h[1]; hv.z = h[2]; hv.w = h[3];
        *(float4*)&out[OUT_H + (size_t)b * 512 + r4] = hv;
      }
    }
    ++tgt; gbar(flags, tgt);
  }
}

extern "C" void kernel_launch(void* const* d_in, const int* in_sizes, int n_in,
                              void* d_out, int out_size, void* d_ws, size_t ws_size,
                              hipStream_t stream) {
  (void)in_sizes; (void)n_in; (void)out_size; (void)ws_size;
  const float* emb    = (const float*)d_in[0];
  const float* dec_in = (const float*)d_in[1];
  const float* dec_h  = (const float*)d_in[2];
  const float* dec_c  = (const float*)d_in[3];
  const float* ctx_in = (const float*)d_in[4];
  const float* W_i2h  = (const float*)d_in[5];
  const float* b_i2h  = (const float*)d_in[6];
  const float* W_h2h  = (const float*)d_in[7];
  const float* b_h2h  = (const float*)d_in[8];
  const float* W_out  = (const float*)d_in[9];
  const float* b_out  = (const float*)d_in[10];
  const float* W_inp  = (const float*)d_in[11];
  const float* b_inp  = (const float*)d_in[12];
  const float* W_ctx  = (const float*)d_in[13];
  const float* b_ctx  = (const float*)d_in[14];
  const float* Vv     = (const float*)d_in[15];
  float* out = (float*)d_out;
  float* ws  = (float*)d_ws;

  k_ctx<<<dim3(512, 8), 256, 0, stream>>>(ctx_in, W_ctx, b_ctx, ws);
  k_init<<<386, 256, 0, stream>>>(dec_h, dec_in, ws);
  k_main<<<NBLK, NTHR, 0, stream>>>(W_i2h, b_i2h, W_h2h, b_h2h, W_out, b_out,
                                    W_inp, b_inp, Vv, emb, dec_c, ws, out);
}

// Round 7
// 18971.461 us; speedup vs baseline: 4.0578x; 1.2081x over previous
//
#include <hip/hip_runtime.h>

#define B 128
#define L 256
#define E 256
#define H 512
#define NBLK 256
#define NTHR 512

typedef float f4 __attribute__((ext_vector_type(4)));

// ---- ws float offsets ----
#define WS_CTX 0u          // [B][L][H] = 16777216 floats
#define WS_HT  18874368u   // [B][512] lstm h_t
#define WS_HH  18939904u   // [B][512] h carry
#define WS_HID 19005440u   // [B][512] attn context
#define WS_INP 19071232u   // [B][512] attn query  (note: moved, no overlap)
#define WS_XT  19136768u   // [B][256] current x
#define WS_FLG 19169536u   // flags region (uints): flags[0..255], gen at [320]

// ---- d_out float offsets ----
#define OUT_ALPHA 0u
#define OUT_PTR   8388608u
#define OUT_H     8421376u
#define OUT_C     8486912u

#define L2E 1.4426950408889634f

__device__ __forceinline__ float fast_rcp(float x) { return __builtin_amdgcn_rcpf(x); }

__device__ __forceinline__ float ftanh(float x) {
  float e = exp2f(x * (2.0f * L2E));
  return 1.0f - 2.0f * fast_rcp(e + 1.0f);
}
__device__ __forceinline__ float fsig(float x) {
  float e = exp2f(-x * L2E);
  return fast_rcp(1.0f + e);
}

// ==== batched coherent loads: N x dwordx4 + vmcnt(0) inside ONE asm block ====
#define CLD1(v0, p0)                                                          \
  asm volatile("global_load_dwordx4 %0, %1, off sc0 sc1\n\t"                  \
               "s_waitcnt vmcnt(0)"                                           \
               : "=&v"(v0) : "v"(p0) : "memory")

#define CLD2(va, pa)                                                          \
  asm volatile("global_load_dwordx4 %0, %2, off sc0 sc1\n\t"                  \
               "global_load_dwordx4 %1, %3, off sc0 sc1\n\t"                  \
               "s_waitcnt vmcnt(0)"                                           \
               : "=&v"(va[0]), "=&v"(va[1])                                   \
               : "v"(pa[0]), "v"(pa[1]) : "memory")

#define CLD4(va, pa)                                                          \
  asm volatile("global_load_dwordx4 %0, %4, off sc0 sc1\n\t"                  \
               "global_load_dwordx4 %1, %5, off sc0 sc1\n\t"                  \
               "global_load_dwordx4 %2, %6, off sc0 sc1\n\t"                  \
               "global_load_dwordx4 %3, %7, off sc0 sc1\n\t"                  \
               "s_waitcnt vmcnt(0)"                                           \
               : "=&v"(va[0]), "=&v"(va[1]), "=&v"(va[2]), "=&v"(va[3])       \
               : "v"(pa[0]), "v"(pa[1]), "v"(pa[2]), "v"(pa[3]) : "memory")

#define CLD6(va, pa)                                                          \
  asm volatile("global_load_dwordx4 %0, %6, off sc0 sc1\n\t"                  \
               "global_load_dwordx4 %1, %7, off sc0 sc1\n\t"                  \
               "global_load_dwordx4 %2, %8, off sc0 sc1\n\t"                  \
               "global_load_dwordx4 %3, %9, off sc0 sc1\n\t"                  \
               "global_load_dwordx4 %4, %10, off sc0 sc1\n\t"                 \
               "global_load_dwordx4 %5, %11, off sc0 sc1\n\t"                 \
               "s_waitcnt vmcnt(0)"                                           \
               : "=&v"(va[0]), "=&v"(va[1]), "=&v"(va[2]), "=&v"(va[3]),      \
                 "=&v"(va[4]), "=&v"(va[5])                                   \
               : "v"(pa[0]), "v"(pa[1]), "v"(pa[2]), "v"(pa[3]),              \
                 "v"(pa[4]), "v"(pa[5]) : "memory")

// ==== coherent packed stores (expcnt fence keeps data regs live) ====
#define CST4_1(p0, v0)                                                        \
  asm volatile("global_store_dwordx4 %0, %1, off sc0 sc1\n\t"                 \
               "s_waitcnt expcnt(0)"                                          \
               :: "v"(p0), "v"(v0) : "memory")

// ---- hierarchical barrier: flags -> block0 aggregates -> gen broadcast ----
__device__ __forceinline__ void gbar(unsigned* flags, unsigned tgt) {
  asm volatile("s_waitcnt vmcnt(0) lgkmcnt(0) expcnt(0)" ::: "memory");
  __syncthreads();
  if (threadIdx.x == 0) {
    unsigned* p = flags + blockIdx.x;
    asm volatile("global_store_dword %0, %1, off sc0 sc1" :: "v"(p), "v"(tgt) : "memory");
  }
  if (blockIdx.x == 0) {
    if (threadIdx.x < 64) {
      const unsigned* fp = flags + threadIdx.x * 4;
      for (;;) {
        unsigned f0, f1, f2, f3;
        asm volatile("global_load_dwordx4 v[20:23], %4, off sc0 sc1\n\t"
                     "s_waitcnt vmcnt(0)\n\t"
                     "v_mov_b32 %0, v20\n\t"
                     "v_mov_b32 %1, v21\n\t"
                     "v_mov_b32 %2, v22\n\t"
                     "v_mov_b32 %3, v23"
                     : "=v"(f0), "=v"(f1), "=v"(f2), "=v"(f3)
                     : "v"(fp) : "memory", "v20", "v21", "v22", "v23");
        bool ok = (f0 >= tgt) && (f1 >= tgt) && (f2 >= tgt) && (f3 >= tgt);
        if (__all(ok)) break;
        __builtin_amdgcn_s_sleep(1);
      }
    }
    __syncthreads();
    if (threadIdx.x == 0) {
      unsigned* gp = flags + 320;
      asm volatile("global_store_dword %0, %1, off sc0 sc1" :: "v"(gp), "v"(tgt) : "memory");
    }
  } else {
    if (threadIdx.x == 0) {
      const unsigned* gp = flags + 320;
      for (;;) {
        unsigned g;
        asm volatile("global_load_dword %0, %1, off sc0 sc1\n\ts_waitcnt vmcnt(0)"
                     : "=&v"(g) : "v"(gp) : "memory");
        if (g >= tgt) break;
        __builtin_amdgcn_s_sleep(4);
      }
    }
  }
  __syncthreads();
}

// ================= precompute ctx[b][l][g] (proven) =================
__global__ __launch_bounds__(256) void k_ctx(const float* __restrict__ context,
                                             const float* __restrict__ Wc,
                                             const float* __restrict__ bc,
                                             float* __restrict__ ws) {
  __shared__ float a_lds[64][33];
  __shared__ float b_lds[32][68];
  int t = threadIdx.x;
  int m0 = blockIdx.x * 64;
  int n0 = blockIdx.y * 64;
  int tx = t & 15, ty = t >> 4;
  float acc[4][4] = {};
  for (int kc = 0; kc < 16; ++kc) {
    int k0 = kc * 32;
    __syncthreads();
#pragma unroll
    for (int i = 0; i < 2; ++i) {
      int f40 = t + i * 256;
      int mm = f40 >> 3;
      int k4 = (f40 & 7) * 4;
      float4 v = *(const float4*)&context[(size_t)(m0 + mm) * H + k0 + k4];
      a_lds[mm][k4] = v.x; a_lds[mm][k4 + 1] = v.y; a_lds[mm][k4 + 2] = v.z; a_lds[mm][k4 + 3] = v.w;
    }
#pragma unroll
    for (int i = 0; i < 2; ++i) {
      int f40 = t + i * 256;
      int nn = f40 >> 3;
      int k4 = (f40 & 7) * 4;
      float4 v = *(const float4*)&Wc[(size_t)(n0 + nn) * H + k0 + k4];
      b_lds[k4][nn] = v.x; b_lds[k4 + 1][nn] = v.y; b_lds[k4 + 2][nn] = v.z; b_lds[k4 + 3][nn] = v.w;
    }
    __syncthreads();
#pragma unroll
    for (int kk = 0; kk < 32; ++kk) {
      float4 bv = *(const float4*)&b_lds[kk][tx * 4];
      float a0 = a_lds[ty * 4 + 0][kk], a1 = a_lds[ty * 4 + 1][kk];
      float a2 = a_lds[ty * 4 + 2][kk], a3 = a_lds[ty * 4 + 3][kk];
      acc[0][0] += a0 * bv.x; acc[0][1] += a0 * bv.y; acc[0][2] += a0 * bv.z; acc[0][3] += a0 * bv.w;
      acc[1][0] += a1 * bv.x; acc[1][1] += a1 * bv.y; acc[1][2] += a1 * bv.z; acc[1][3] += a1 * bv.w;
      acc[2][0] += a2 * bv.x; acc[2][1] += a2 * bv.y; acc[2][2] += a2 * bv.z; acc[2][3] += a2 * bv.w;
      acc[3][0] += a3 * bv.x; acc[3][1] += a3 * bv.y; acc[3][2] += a3 * bv.z; acc[3][3] += a3 * bv.w;
    }
  }
  float b0v = bc[n0 + tx * 4], b1v = bc[n0 + tx * 4 + 1], b2v = bc[n0 + tx * 4 + 2], b3v = bc[n0 + tx * 4 + 3];
#pragma unroll
  for (int i = 0; i < 4; ++i) {
    size_t o = WS_CTX + (size_t)(m0 + ty * 4 + i) * H + n0 + tx * 4;
    float4 v; v.x = acc[i][0] + b0v; v.y = acc[i][1] + b1v; v.z = acc[i][2] + b2v; v.w = acc[i][3] + b3v;
    *(float4*)&ws[o] = v;
  }
}

// ================= init: HH=dec_h, XT=dec_in, flags=0 =================
__global__ __launch_bounds__(256) void k_init(const float* __restrict__ dec_h,
                                              const float* __restrict__ dec_in,
                                              float* __restrict__ ws) {
  int flat = blockIdx.x * 256 + threadIdx.x;
  if (flat < 65536) {
    ws[WS_HH + flat] = dec_h[flat];
  } else if (flat < 98304) {
    ws[WS_XT + (flat - 65536)] = dec_in[flat - 65536];
  } else if (flat < 98816) {
    ((unsigned*)(ws + WS_FLG))[flat - 98304] = 0u;
  }
}

// ================= persistent fused decoder: 4 phases, no partials =================
__global__ __launch_bounds__(512, 1) void k_main(
    const float* __restrict__ Wi2h, const float* __restrict__ bi2h,
    const float* __restrict__ Wh2h, const float* __restrict__ bh2h,
    const float* __restrict__ Wout, const float* __restrict__ bout,
    const float* __restrict__ Winp, const float* __restrict__ binp,
    const float* __restrict__ Vv,   const float* __restrict__ emb,
    const float* __restrict__ dec_c,
    float* __restrict__ ws,         float* __restrict__ out) {
  __shared__ float s_act[13504];     // PG: acts[16][772] + gates[64][17] @12352
  __shared__ float s_maskP[256];
  __shared__ float s_mw[8], s_dw[8];
  __shared__ float s_red[4];
  __shared__ int   s_redi[4];
  __shared__ int   s_wc[4], s_wb[4];
  __shared__ int   s_mi, s_cnt;

  unsigned* flags = (unsigned*)(ws + WS_FLG);
  const int bid = blockIdx.x;
  const int t = threadIdx.x;
  const int wv = t >> 6, ln = t & 63;
  unsigned tgt = 0;

  float creg = 0.f;   // c-state: thread t<256 of PG block owns (u,b)

  if (bid < 128 && t < 256) s_maskP[t] = 1.0f;
  __syncthreads();

  for (int step = 0; step < L; ++step) {
    // ======== PG: gates + LSTM fused; 32 j-tiles(16u x 4g) x 8 b-tiles(16b) ========
    {
      const int jt = bid >> 3, bt = bid & 7;
      const int u0 = jt * 16, b0 = bt * 16;
      float* sact = s_act;            // [16][772]
      float* sg   = s_act + 12352;    // [64][17]
      f4 va[6]; const float* pa[6]; int sb[6], sq[6];
#pragma unroll
      for (int it = 0; it < 6; ++it) {
        unsigned c = (unsigned)(t + it * 512);
        int bl = (int)(c / 192u);
        int kq = (int)(c - (unsigned)bl * 192u);
        int kg = kq * 4;
        sb[it] = bl; sq[it] = kq;
        pa[it] = (kg < 256) ? ws + WS_XT + (size_t)(b0 + bl) * 256 + kg
                            : ws + WS_HH + (size_t)(b0 + bl) * 512 + (kg - 256);
      }
      CLD6(va, pa);
      __builtin_amdgcn_sched_barrier(0);
#pragma unroll
      for (int it = 0; it < 6; ++it) *(f4*)&sact[sb[it] * 772 + sq[it] * 4] = va[it];
      __syncthreads();

      const int jj = t >> 4, bb = t & 15;
      const int g = jj >> 3, up = (jj & 7) * 2;
      const int r0 = g * 512 + u0 + up;
      float a0 = 0.f, a1 = 0.f;
      {
        const float* w0 = Wi2h + (size_t)r0 * 256;
        const float* w1 = w0 + 256;
        const float* sa = sact + bb * 772;
#pragma unroll 8
        for (int k4 = 0; k4 < 64; ++k4) {
          float4 x = *(const float4*)&sa[k4 * 4];
          float4 p = *(const float4*)&w0[k4 * 4];
          float4 q = *(const float4*)&w1[k4 * 4];
          a0 += p.x * x.x + p.y * x.y + p.z * x.z + p.w * x.w;
          a1 += q.x * x.x + q.y * x.y + q.z * x.z + q.w * x.w;
        }
        const float* v0 = Wh2h + (size_t)r0 * 512;
        const float* v1 = v0 + 512;
        const float* shh = sa + 256;
#pragma unroll 8
        for (int k4 = 0; k4 < 128; ++k4) {
          float4 x = *(const float4*)&shh[k4 * 4];
          float4 p = *(const float4*)&v0[k4 * 4];
          float4 q = *(const float4*)&v1[k4 * 4];
          a0 += p.x * x.x + p.y * x.y + p.z * x.z + p.w * x.w;
          a1 += q.x * x.x + q.y * x.y + q.z * x.z + q.w * x.w;
        }
      }
      sg[(g * 16 + up) * 17 + bb]     = a0;
      sg[(g * 16 + up + 1) * 17 + bb] = a1;
      __syncthreads();
      if (t < 256) {
        const int uu = t >> 4, b2 = t & 15;
        const int j0 = u0 + uu;
        float si_ = sg[(     uu) * 17 + b2] + bi2h[       j0] + bh2h[       j0];
        float sf_ = sg[(16 + uu) * 17 + b2] + bi2h[ 512 + j0] + bh2h[ 512 + j0];
        float sg_ = sg[(32 + uu) * 17 + b2] + bi2h[1024 + j0] + bh2h[1024 + j0];
        float so_ = sg[(48 + uu) * 17 + b2] + bi2h[1536 + j0] + bh2h[1536 + j0];
        if (step == 0) creg = dec_c[(size_t)(b0 + b2) * 512 + j0];
        float cn = fsig(sf_) * creg + fsig(si_) * ftanh(sg_);
        creg = cn;
        float htv = fsig(so_) * ftanh(cn);
        s_act[b2 * 17 + uu] = htv;   // pack buffer [16b][16u+pad]
        if (step == L - 1) out[OUT_C + (size_t)(b0 + b2) * 512 + j0] = cn;
      }
      __syncthreads();
      if (t < 64) {
        const int b2 = t >> 2, q = t & 3;
        f4 hv;
        hv[0] = s_act[b2 * 17 + q * 4 + 0];
        hv[1] = s_act[b2 * 17 + q * 4 + 1];
        hv[2] = s_act[b2 * 17 + q * 4 + 2];
        hv[3] = s_act[b2 * 17 + q * 4 + 3];
        float* hp = ws + WS_HT + (size_t)(b0 + b2) * 512 + u0 + q * 4;
        CST4_1(hp, hv);
      }
    }
    ++tgt; gbar(flags, tgt);

    // ======== PI: inp = Winp @ h_t + binp; 16 g-tiles(32) x 16 b-tiles(8) ========
    {
      const int gt = bid >> 4, bt = bid & 15;
      const int g0 = gt * 32, b0 = bt * 8;
      float* si = s_act;               // [8][516]
      float* stmp = s_act + 4128;      // [8][33]
      f4 va[2]; const float* pa[2];
#pragma unroll
      for (int it = 0; it < 2; ++it) {
        int c = t + it * 512;
        int bl = c >> 7, kq = c & 127;
        pa[it] = ws + WS_HT + (size_t)(b0 + bl) * 512 + kq * 4;
      }
      CLD2(va, pa);
      __builtin_amdgcn_sched_barrier(0);
#pragma unroll
      for (int it = 0; it < 2; ++it) {
        int c = t + it * 512;
        int bl = c >> 7, kq = c & 127;
        *(f4*)&si[bl * 516 + kq * 4] = va[it];
      }
      __syncthreads();
      if (t < 256) {
        const int gl = t >> 3, bb = t & 7;
        const float* w = Winp + (size_t)(g0 + gl) * 512;
        const float* sa = si + bb * 516;
        float acc = 0.f;
#pragma unroll 8
        for (int k4 = 0; k4 < 128; ++k4) {
          float4 ww = *(const float4*)&w[k4 * 4];
          float4 xx = *(const float4*)&sa[k4 * 4];
          acc += ww.x * xx.x + ww.y * xx.y + ww.z * xx.z + ww.w * xx.w;
        }
        stmp[bb * 33 + gl] = acc + binp[g0 + gl];
      }
      __syncthreads();
      if (t < 64) {
        const int bb = t >> 3, q = t & 7;
        f4 v;
        v[0] = stmp[bb * 33 + q * 4 + 0];
        v[1] = stmp[bb * 33 + q * 4 + 1];
        v[2] = stmp[bb * 33 + q * 4 + 2];
        v[3] = stmp[bb * 33 + q * 4 + 3];
        float* p = ws + WS_INP + (size_t)(b0 + bb) * 512 + g0 + q * 4;
        CST4_1(p, v);
      }
    }
    ++tgt; gbar(flags, tgt);

    // ======== PA: attention (blocks 0..127), fused single ctx pass ========
    if (bid < 128) {
      const int b = bid;
      float* s_inp  = s_act;                 // 512
      float* s_sc   = s_act + 512;           // 256
      int*   s_li   = (int*)(s_act + 768);   // 256
      float* s_hidp = s_act + 1024;          // 8*512
      float* s_out  = s_act + 5120;          // 512
      if (t < 128) {
        f4 v;
        const float* p = ws + WS_INP + (size_t)b * 512 + t * 4;
        CLD1(v, p);
        *(f4*)&s_inp[t * 4] = v;
      }
      __syncthreads();
      const int d0 = ln * 8;
      float inp8[8], v8[8];
#pragma unroll
      for (int i = 0; i < 8; ++i) { inp8[i] = s_inp[d0 + i]; v8[i] = Vv[d0 + i]; }
      bool validl = (t < 256) && (s_maskP[t] != 0.f);
      unsigned long long bal = __ballot(validl);
      if (t < 256 && (t & 63) == 0) s_wc[t >> 6] = (int)__popcll(bal);
      __syncthreads();
      if (t == 0) {
        int base = 0;
#pragma unroll
        for (int i = 0; i < 4; ++i) { s_wb[i] = base; base += s_wc[i]; }
        s_cnt = base;
      }
      __syncthreads();
      if (validl) {
        int idx = s_wb[t >> 6] + (int)__popcll(bal & ((1ull << (t & 63)) - 1ull));
        s_li[idx] = t;
      }
      __syncthreads();
      const int cnt = s_cnt;
      float m = -INFINITY, den = 0.f;
      float hid[8] = {0, 0, 0, 0, 0, 0, 0, 0};
      {
        int slot = wv;
        int l = 0; f4 c0 = {0, 0, 0, 0}, c1 = c0;
        if (slot < cnt) {
          l = s_li[slot];
          const float* cp = ws + WS_CTX + ((size_t)(b * 256 + l) * 512) + d0;
          c0 = *(const f4*)cp; c1 = *(const f4*)(cp + 4);
        }
        while (slot < cnt) {
          const int nslot = slot + 8;
          int nl = 0; f4 n0 = {0, 0, 0, 0}, n1 = n0;
          if (nslot < cnt) {
            nl = s_li[nslot];
            const float* np = ws + WS_CTX + ((size_t)(b * 256 + nl) * 512) + d0;
            n0 = *(const f4*)np; n1 = *(const f4*)(np + 4);
          }
          float part = v8[0] * ftanh(inp8[0] + c0[0]) + v8[1] * ftanh(inp8[1] + c0[1])
                     + v8[2] * ftanh(inp8[2] + c0[2]) + v8[3] * ftanh(inp8[3] + c0[3])
                     + v8[4] * ftanh(inp8[4] + c1[0]) + v8[5] * ftanh(inp8[5] + c1[1])
                     + v8[6] * ftanh(inp8[6] + c1[2]) + v8[7] * ftanh(inp8[7] + c1[3]);
#pragma unroll
          for (int off = 32; off > 0; off >>= 1) part += __shfl_xor(part, off);
          if (ln == 0) s_sc[l] = part;
          float mn = fmaxf(m, part);
          float scale = exp2f((m - mn) * L2E);
          float e = exp2f((part - mn) * L2E);
          den = den * scale + e;
          hid[0] = hid[0] * scale + e * c0[0]; hid[1] = hid[1] * scale + e * c0[1];
          hid[2] = hid[2] * scale + e * c0[2]; hid[3] = hid[3] * scale + e * c0[3];
          hid[4] = hid[4] * scale + e * c1[0]; hid[5] = hid[5] * scale + e * c1[1];
          hid[6] = hid[6] * scale + e * c1[2]; hid[7] = hid[7] * scale + e * c1[3];
          m = mn;
          c0 = n0; c1 = n1; l = nl; slot = nslot;
        }
      }
      if (ln == 0) { s_mw[wv] = m; s_dw[wv] = den; }
      __syncthreads();
      float M = s_mw[0];
#pragma unroll
      for (int w = 1; w < 8; ++w) M = fmaxf(M, s_mw[w]);
      float D = 0.f;
#pragma unroll
      for (int w = 0; w < 8; ++w) D += s_dw[w] * exp2f((s_mw[w] - M) * L2E);
      float fac = exp2f((m - M) * L2E);
#pragma unroll
      for (int i = 0; i < 8; ++i) s_hidp[wv * 512 + d0 + i] = hid[i] * fac;
      __syncthreads();
      const float rD = 1.0f / D;
      {
        float hs = 0.f;
#pragma unroll
        for (int w = 0; w < 8; ++w) hs += s_hidp[w * 512 + t];
        s_out[t] = hs * rD;
      }
      float sc = 0.f; bool valid = false;
      if (t < 256) {
        valid = (s_maskP[t] != 0.f);
        sc = s_sc[t];
        float alpha = valid ? exp2f((sc - M) * L2E) * rD : 0.f;
        out[OUT_ALPHA + ((size_t)b * 256 + step) * 256 + t] = alpha;
        float bs = valid ? sc : -INFINITY;
        int bi = t;
#pragma unroll
        for (int off = 32; off > 0; off >>= 1) {
          float os = __shfl_down(bs, off);
          int oi = __shfl_down(bi, off);
          if (os > bs || (os == bs && oi < bi)) { bs = os; bi = oi; }
        }
        if ((t & 63) == 0) { s_red[t >> 6] = bs; s_redi[t >> 6] = bi; }
      }
      __syncthreads();
      if (t == 0) {
        float mm = s_red[0]; int mi = s_redi[0];
#pragma unroll
        for (int w = 1; w < 4; ++w) {
          if (s_red[w] > mm || (s_red[w] == mm && s_redi[w] < mi)) { mm = s_red[w]; mi = s_redi[w]; }
        }
        s_mi = mi;
      }
      __syncthreads();
      const int mi = s_mi;
      if (t < 128) {
        f4 hv = *(const f4*)&s_out[t * 4];
        float* hp = ws + WS_HID + (size_t)b * 512 + t * 4;
        CST4_1(hp, hv);
      }
      if (t < 64) {
        float4 xv = *(const float4*)&emb[((size_t)b * 256 + mi) * 256 + t * 4];
        f4 xq; xq[0] = xv.x; xq[1] = xv.y; xq[2] = xv.z; xq[3] = xv.w;
        float* xp = ws + WS_XT + (size_t)b * 256 + t * 4;
        CST4_1(xp, xq);
      }
      if (t == 0) {
        out[OUT_PTR + (size_t)b * 256 + step] = (float)mi;
        s_maskP[mi] = 0.f;
      }
    }
    ++tgt; gbar(flags, tgt);

    // ======== PH: h_new = tanh(Wout@[hid;ht]+bout); 16 r-tiles(32) x 16 b-tiles(8) ========
    {
      const int rt = bid >> 4, bt = bid & 15;
      const int r0 = rt * 32, b0 = bt * 8;
      float* sh = s_act;               // [8][1028]
      float* stmp = s_act + 8224;      // [8][33]
      f4 va[4]; const float* pa[4];
#pragma unroll
      for (int it = 0; it < 4; ++it) {
        int c = t + it * 512;
        int bl = c >> 8, kq = c & 255;
        int kg = kq * 4;
        pa[it] = (kg < 512) ? ws + WS_HID + (size_t)(b0 + bl) * 512 + kg
                            : ws + WS_HT + (size_t)(b0 + bl) * 512 + (kg - 512);
      }
      CLD4(va, pa);
      __builtin_amdgcn_sched_barrier(0);
#pragma unroll
      for (int it = 0; it < 4; ++it) {
        int c = t + it * 512;
        int bl = c >> 8, kq = c & 255;
        *(f4*)&sh[bl * 1028 + kq * 4] = va[it];
      }
      __syncthreads();
      if (t < 256) {
        const int rl = t >> 3, bb = t & 7;
        const float* w = Wout + (size_t)(r0 + rl) * 1024;
        const float* sa = sh + bb * 1028;
        float acc = 0.f;
#pragma unroll 8
        for (int k4 = 0; k4 < 256; ++k4) {
          float4 ww = *(const float4*)&w[k4 * 4];
          float4 xx = *(const float4*)&sa[k4 * 4];
          acc += ww.x * xx.x + ww.y * xx.y + ww.z * xx.z + ww.w * xx.w;
        }
        float h = ftanh(acc + bout[r0 + rl]);
        stmp[bb * 33 + rl] = h;
        if (step == L - 1) out[OUT_H + (size_t)(b0 + bb) * 512 + r0 + rl] = h;
      }
      __syncthreads();
      if (t < 64) {
        const int bb = t >> 3, q = t & 7;
        f4 v;
        v[0] = stmp[bb * 33 + q * 4 + 0];
        v[1] = stmp[bb * 33 + q * 4 + 1];
        v[2] = stmp[bb * 33 + q * 4 + 2];
        v[3] = stmp[bb * 33 + q * 4 + 3];
        float* p = ws + WS_HH + (size_t)(b0 + bb) * 512 + r0 + q * 4;
        CST4_1(p, v);
      }
    }
    ++tgt; gbar(flags, tgt);
  }
}

extern "C" void kernel_launch(void* const* d_in, const int* in_sizes, int n_in,
                              void* d_out, int out_size, void* d_ws, size_t ws_size,
                              hipStream_t stream) {
  (void)in_sizes; (void)n_in; (void)out_size; (void)ws_size;
  const float* emb    = (const float*)d_in[0];
  const float* dec_in = (const float*)d_in[1];
  const float* dec_h  = (const float*)d_in[2];
  const float* dec_c  = (const float*)d_in[3];
  const float* ctx_in = (const float*)d_in[4];
  const float* W_i2h  = (const float*)d_in[5];
  const float* b_i2h  = (const float*)d_in[6];
  const float* W_h2h  = (const float*)d_in[7];
  const float* b_h2h  = (const float*)d_in[8];
  const float* W_out  = (const float*)d_in[9];
  const float* b_out  = (const float*)d_in[10];
  const float* W_inp  = (const float*)d_in[11];
  const float* b_inp  = (const float*)d_in[12];
  const float* W_ctx  = (const float*)d_in[13];
  const float* b_ctx  = (const float*)d_in[14];
  const float* Vv     = (const float*)d_in[15];
  float* out = (float*)d_out;
  float* ws  = (float*)d_ws;

  k_ctx<<<dim3(512, 8), 256, 0, stream>>>(ctx_in, W_ctx, b_ctx, ws);
  k_init<<<386, 256, 0, stream>>>(dec_h, dec_in, ws);
  k_main<<<NBLK, NTHR, 0, stream>>>(W_i2h, b_i2h, W_h2h, b_h2h, W_out, b_out,
                                    W_inp, b_inp, Vv, emb, dec_c, ws, out);
}